// Round 5
// baseline (601.814 us; speedup 1.0000x reference)
//
#include <hip/hip_runtime.h>

#define PFD 8   // prefetch depth (statically indexed ring, unrolled x8)

constexpr int Bv = 2, Tv = 4096, Hv = 8, Kv = 64, Vv = 64;

// full sum over each contiguous 16-lane row via DPP (VALU only, no DS ops)
__device__ __forceinline__ float row16_sum(float x) {
    int t;
    t = __builtin_amdgcn_update_dpp(0, __float_as_int(x), 0x128, 0xF, 0xF, true); // row_ror:8
    x += __int_as_float(t);
    t = __builtin_amdgcn_update_dpp(0, __float_as_int(x), 0x124, 0xF, 0xF, true); // row_ror:4
    x += __int_as_float(t);
    t = __builtin_amdgcn_update_dpp(0, __float_as_int(x), 0x4E, 0xF, 0xF, true);  // quad_perm [2,3,0,1]
    x += __int_as_float(t);
    t = __builtin_amdgcn_update_dpp(0, __float_as_int(x), 0xB1, 0xF, 0xF, true);  // quad_perm [1,0,3,2]
    x += __int_as_float(t);
    return x;
}

// One recurrence step. s_ = ring slot (compile-time), PF_ = 1 in main loop.
// Order: compute step t from slot s, then prefetch step t+PFD into slot s,
// then sched_barrier(0) — loads cannot sink more than one body => depth >= 7.
#define BODY(s_, PF_) do {                                                      \
    constexpr int s = (s_);                                                     \
    const float dec = __expf(gr[s]);                                            \
    D *= dec;                                                                   \
    const float invD = __builtin_amdgcn_rcpf(D);                                \
    const float bvl  = lkr[s] * bv;          /* lam_k * b_reg  (short path) */  \
    const float bevD = betr[s] * vr[s] * invD;   /* beta*v/D   (off path)  */   \
    float a0 = kr[s].x * S[0], a1 = kr[s].y * S[1];                             \
    a0 = fmaf(kr[s].z, S[2], a0); a1 = fmaf(kr[s].w, S[3], a1);                 \
    const float dot = row16_sum(a0 + a1);                                       \
    /* us = (beta*(v - D*(dot+bvl)))/D, with bevD precomputed off-path */       \
    const float us = fmaf(-betr[s], dot + bvl, bevD);                           \
    S[0] = fmaf(kr[s].x, us, S[0]); S[1] = fmaf(kr[s].y, us, S[1]);             \
    S[2] = fmaf(kr[s].z, us, S[2]); S[3] = fmaf(kr[s].w, us, S[3]);             \
    bv = fmaf(lkr[s], us, bv);                                                  \
    float o0 = qr[s].x * S[0], o1 = qr[s].y * S[1];                             \
    o0 = fmaf(qr[s].z, S[2], o0); o1 = fmaf(qr[s].w, S[3], o1);                 \
    const float od = row16_sum(o0 + o1);                                        \
    op[col] = D * fmaf(0.125f, od, lqr[s] * bv);  /* 16 dup lanes, same val */  \
    op += HV;                                                                   \
    if (PF_) {  /* prefetch step t+PFD into slot s (just consumed) */           \
        kr[s] = *(const float4*)(klp + (ksub << 2));                            \
        qr[s] = *(const float4*)(qlp + (ksub << 2));                            \
        vr[s] = vlp[col];                                                       \
        gr[s] = glp[0]; betr[s] = blp[0]; lqr[s] = lqlp[0]; lkr[s] = lklp[0];   \
        klp += HK; qlp += HK; vlp += HV;                                        \
        glp += Hv; blp += Hv; lqlp += Hv; lklp += Hv;                           \
        __builtin_amdgcn_sched_barrier(0);                                      \
    }                                                                           \
} while (0)

__global__ __launch_bounds__(64, 1)
void gdr1dc_kernel(const float* __restrict__ qg, const float* __restrict__ kg,
                   const float* __restrict__ vg, const float* __restrict__ gg,
                   const float* __restrict__ bg, const float* __restrict__ lqg,
                   const float* __restrict__ lkg, const float* __restrict__ S0,
                   const float* __restrict__ b0,
                   float* __restrict__ o_out, float* __restrict__ S_out,
                   float* __restrict__ b_out)
{
    const int bid  = blockIdx.x;
    // XCD swizzle: bid%8 = XCD (round-robin dispatch). Keep all 16 column-group
    // blocks of one (b,h) on one XCD so they share k/q in that XCD's L2.
    const int slot = bid >> 3;                    // 0..31
    const int bh   = (bid & 7) + 8 * (slot >> 4); // b*H + h
    const int cg   = slot & 15;                   // column group (4 cols each)
    const int lane = threadIdx.x;                 // 0..63
    const int ksub = lane & 15;                   // which 4-slice of K
    const int col  = cg * 4 + (lane >> 4);        // output column v in [0,64)

    // state: this lane owns S[ksub*4 + j][col]; kept as S_true = D * S_reg
    float S[4];
#pragma unroll
    for (int j = 0; j < 4; ++j)
        S[j] = S0[((size_t)bh * Kv + (ksub * 4 + j)) * Vv + col];
    float bv = b0[(size_t)bh * Vv + col];   // replicated across the 16 row-lanes
    float D  = 1.0f;                        // running decay product (rescaled)

    const int b = bh / Hv, h = bh % Hv;
    const size_t t0 = (size_t)b * Tv * Hv + h;   // flat [b,t=0,h] index
    const int HK = Hv * Kv, HV = Hv * Vv;

    const float* klp  = kg  + t0 * Kv;
    const float* qlp  = qg  + t0 * Kv;
    const float* vlp  = vg  + t0 * Vv;
    const float* glp  = gg  + t0;            // uniform -> s_load
    const float* blp  = bg  + t0;
    const float* lqlp = lqg + t0;
    const float* lklp = lkg + t0;
    float*       op   = o_out + t0 * Vv;

    float4 kr[PFD], qr[PFD];
    float  vr[PFD], gr[PFD], betr[PFD], lqr[PFD], lkr[PFD];

    // prologue: slots 0..7 <- steps 0..7; pointers end at step 8
#pragma unroll
    for (int p = 0; p < PFD; ++p) {
        kr[p] = *(const float4*)(klp + (ksub << 2));
        qr[p] = *(const float4*)(qlp + (ksub << 2));
        vr[p] = vlp[col];
        gr[p] = glp[0]; betr[p] = blp[0]; lqr[p] = lqlp[0]; lkr[p] = lklp[0];
        klp += HK; qlp += HK; vlp += HV; glp += Hv; blp += Hv; lqlp += Hv; lklp += Hv;
    }

    // main loop: 511 groups of 8 steps, unconditional in-bounds prefetch
    for (int tt = 0; tt < Tv - PFD; tt += PFD) {
        if ((tt & 31) == 0 && tt) {   // rescale every 32 steps: |1/D| <= e^32
#pragma unroll
            for (int j = 0; j < 4; ++j) S[j] *= D;
            bv *= D; D = 1.0f;
        }
        BODY(0, 1); BODY(1, 1); BODY(2, 1); BODY(3, 1);
        BODY(4, 1); BODY(5, 1); BODY(6, 1); BODY(7, 1);
    }
    // epilogue: last 8 steps, no prefetch
    BODY(0, 0); BODY(1, 0); BODY(2, 0); BODY(3, 0);
    BODY(4, 0); BODY(5, 0); BODY(6, 0); BODY(7, 0);

    // final state outputs (un-scale)
#pragma unroll
    for (int j = 0; j < 4; ++j)
        S_out[((size_t)bh * Kv + (ksub * 4 + j)) * Vv + col] = D * S[j];
    b_out[(size_t)bh * Vv + col] = D * bv;   // dup lanes, same value
}

extern "C" void kernel_launch(void* const* d_in, const int* in_sizes, int n_in,
                              void* d_out, int out_size, void* d_ws, size_t ws_size,
                              hipStream_t stream) {
    const float* q   = (const float*)d_in[0];
    const float* k   = (const float*)d_in[1];
    const float* v   = (const float*)d_in[2];
    const float* g   = (const float*)d_in[3];
    const float* bet = (const float*)d_in[4];
    const float* lq  = (const float*)d_in[5];
    const float* lk  = (const float*)d_in[6];
    const float* S0  = (const float*)d_in[7];
    const float* b0  = (const float*)d_in[8];

    float* out   = (float*)d_out;
    float* o_out = out;
    float* S_out = out + (size_t)Bv * Tv * Hv * Vv;
    float* b_out = S_out + (size_t)Bv * Hv * Kv * Vv;

    dim3 grid(Bv * Hv * 16);   // (b,h) x 16 column-groups = 256 blocks (1/CU)
    dim3 block(64);
    gdr1dc_kernel<<<grid, block, 0, stream>>>(q, k, v, g, bet, lq, lk, S0, b0,
                                              o_out, S_out, b_out);
}

// Round 6
// 486.350 us; speedup vs baseline: 1.2374x; 1.2374x over previous
//
#include <hip/hip_runtime.h>
#include <stdint.h>

constexpr int Bv = 2, Tv = 4096, Hv = 8, Kv = 64, Vv = 64;
constexpr int CH = 32;            // steps per staged chunk
constexpr int NCH = Tv / CH;      // 128 chunks

// full sum over each contiguous 16-lane row via DPP (VALU only, no DS ops)
__device__ __forceinline__ float row16_sum(float x) {
    int t;
    t = __builtin_amdgcn_update_dpp(0, __float_as_int(x), 0x128, 0xF, 0xF, true); // row_ror:8
    x += __int_as_float(t);
    t = __builtin_amdgcn_update_dpp(0, __float_as_int(x), 0x124, 0xF, 0xF, true); // row_ror:4
    x += __int_as_float(t);
    t = __builtin_amdgcn_update_dpp(0, __float_as_int(x), 0x4E, 0xF, 0xF, true);  // quad_perm [2,3,0,1]
    x += __int_as_float(t);
    t = __builtin_amdgcn_update_dpp(0, __float_as_int(x), 0xB1, 0xF, 0xF, true);  // quad_perm [1,0,3,2]
    x += __int_as_float(t);
    return x;
}

// async global->LDS, no destination VGPRs (CK-style addrspace casts).
// LDS dest = uniform base + lane*size; global src is per-lane.
__device__ __forceinline__ void gl_lds16(const float* g, float* l) {
    __builtin_amdgcn_global_load_lds(
        reinterpret_cast<uint32_t __attribute__((address_space(1)))*>(
            reinterpret_cast<uintptr_t>(g)),
        reinterpret_cast<uint32_t __attribute__((address_space(3)))*>(
            reinterpret_cast<uintptr_t>(l)),
        16, 0, 0);
}
__device__ __forceinline__ void gl_lds4(const float* g, float* l) {
    __builtin_amdgcn_global_load_lds(
        reinterpret_cast<uint32_t __attribute__((address_space(1)))*>(
            reinterpret_cast<uintptr_t>(g)),
        reinterpret_cast<uint32_t __attribute__((address_space(3)))*>(
            reinterpret_cast<uintptr_t>(l)),
        4, 0, 0);
}

// stage chunk -> buffer dd: k,q as 8x 16B-wide loads (4 steps each);
// v,scalars as 2x 4B gathers (16 steps x 4 values each). 20 VMEM ops total.
#define STAGE(dd) do {                                                    \
    _Pragma("unroll")                                                     \
    for (int j = 0; j < 8; ++j) {                                         \
        gl_lds16(kp + j * 4 * Hv * Kv, &k_lds[dd][4 * j][0]);             \
        gl_lds16(qp + j * 4 * Hv * Kv, &q_lds[dd][4 * j][0]);             \
    }                                                                     \
    _Pragma("unroll")                                                     \
    for (int j = 0; j < 2; ++j) {                                         \
        gl_lds4(vp + j * 16 * Hv * Vv, &v_lds[dd][16 * j][0]);            \
        gl_lds4(sp + j * 16 * Hv,      &s_lds[dd][16 * j][0]);            \
    }                                                                     \
    kp += CH * Hv * Kv; qp += CH * Hv * Kv;                               \
    vp += CH * Hv * Vv; sp += CH * Hv;                                    \
} while (0)

// one recurrence step t (compile-time) within the chunk; ring slot s = t&3.
#define BODY(t_, PF_) do {                                                \
    constexpr int t = (t_);                                               \
    constexpr int s = t & 3;                                              \
    const float gt  = scr[s].x, bet = scr[s].y;                           \
    const float lqt = scr[s].z, lkt = scr[s].w;                           \
    const float dec = __expf(gt);                                         \
    Dn *= dec;                                                            \
    const float invD = __builtin_amdgcn_rcpf(Dn);                         \
    const float bvl  = lkt * bv;          /* lam_k * b_reg (short path) */\
    const float bevD = bet * vr[s] * invD;  /* beta*v/D     (off path) */ \
    float a0 = kr[s].x * S[0], a1 = kr[s].y * S[1];                       \
    a0 = fmaf(kr[s].z, S[2], a0); a1 = fmaf(kr[s].w, S[3], a1);           \
    const float dot = row16_sum(a0 + a1);                                 \
    const float us = fmaf(-bet, dot + bvl, bevD);                         \
    S[0] = fmaf(kr[s].x, us, S[0]); S[1] = fmaf(kr[s].y, us, S[1]);       \
    S[2] = fmaf(kr[s].z, us, S[2]); S[3] = fmaf(kr[s].w, us, S[3]);       \
    bv = fmaf(lkt, us, bv);                                               \
    float o0 = qr[s].x * S[0], o1 = qr[s].y * S[1];                       \
    o0 = fmaf(qr[s].z, S[2], o0); o1 = fmaf(qr[s].w, S[3], o1);           \
    const float od = row16_sum(o0 + o1);                                  \
    op[col] = Dn * fmaf(0.125f, od, lqt * bv);  /* dup lanes, same val */ \
    op += HV;                                                             \
    if (PF_) {   /* refill slot s with step t+4 from LDS */               \
        kr[s]  = *(const float4*)&k_lds[d][t + 4][ksub * 4];              \
        qr[s]  = *(const float4*)&q_lds[d][t + 4][ksub * 4];              \
        vr[s]  = v_lds[d][t + 4][c4];                                     \
        scr[s] = *(const float4*)&s_lds[d][t + 4][0];                     \
    }                                                                     \
} while (0)

__global__ __launch_bounds__(64, 1)
void gdr1dc_kernel(const float* __restrict__ qg, const float* __restrict__ kg,
                   const float* __restrict__ vg, const float* __restrict__ gg,
                   const float* __restrict__ bg, const float* __restrict__ lqg,
                   const float* __restrict__ lkg, const float* __restrict__ S0,
                   const float* __restrict__ b0,
                   float* __restrict__ o_out, float* __restrict__ S_out,
                   float* __restrict__ b_out)
{
    const int bid  = blockIdx.x;
    // XCD swizzle: bid%8 = XCD. All 16 column-group blocks of one (b,h)
    // share k/q in that XCD's L2.
    const int slot = bid >> 3;                    // 0..31
    const int bh   = (bid & 7) + 8 * (slot >> 4); // b*H + h
    const int cg   = slot & 15;                   // column group (4 cols)
    const int lane = threadIdx.x;                 // 0..63
    const int ksub = lane & 15;                   // which 4-slice of K
    const int c4   = lane >> 4;                   // 0..3
    const int col  = cg * 4 + c4;                 // output column v

    __shared__ float k_lds[2][CH][Kv];   // 16 KB
    __shared__ float q_lds[2][CH][Kv];   // 16 KB
    __shared__ float v_lds[2][CH][4];    // 1 KB   (this block's 4 cols)
    __shared__ float s_lds[2][CH][4];    // 1 KB   (g, beta, lam_q, lam_k)

    // state: this lane owns S[ksub*4 + j][col]; kept as S_true = Dn * S_reg
    float S[4];
#pragma unroll
    for (int j = 0; j < 4; ++j)
        S[j] = S0[((size_t)bh * Kv + (ksub * 4 + j)) * Vv + col];
    float bv = b0[(size_t)bh * Vv + col];   // replicated across the 16 row-lanes
    float Dn = 1.0f;                        // running decay product

    const int b = bh / Hv, h = bh % Hv;
    const size_t t0 = (size_t)b * Tv * Hv + h;   // flat [b,t=0,h] index
    const int HV = Hv * Vv;

    // per-lane staging source pointers (advanced by STAGE)
    const float* kp = kg + (t0 + (size_t)(lane >> 4) * Hv) * Kv + (lane & 15) * 4;
    const float* qp = qg + (t0 + (size_t)(lane >> 4) * Hv) * Kv + (lane & 15) * 4;
    const float* vp = vg + (t0 + (size_t)(lane >> 2) * Hv) * Vv + cg * 4 + (lane & 3);
    const float* sb = ((lane & 3) == 0) ? gg : ((lane & 3) == 1) ? bg
                    : ((lane & 3) == 2) ? lqg : lkg;
    const float* sp = sb + t0 + (size_t)(lane >> 2) * Hv;
    float*       op = o_out + t0 * Vv;

    float4 kr[4], qr[4], scr[4];
    float  vr[4];

    int d = 0;
    STAGE(0);                                       // chunk 0 -> buf 0
    asm volatile("s_waitcnt vmcnt(0)" ::: "memory");
    __builtin_amdgcn_sched_barrier(0);

    for (int c = 0; c < NCH; ++c) {
        if (c) {   // rescale every 32 steps: |1/Dn| <= e^32
#pragma unroll
            for (int j = 0; j < 4; ++j) S[j] *= Dn;
            bv *= Dn; Dn = 1.0f;
        }
        if (c + 1 < NCH) {          // fire next chunk's async loads first
            STAGE(d ^ 1);
            __builtin_amdgcn_sched_barrier(0);
        }
        // ring prologue: steps 0..3 of this chunk from LDS
#pragma unroll
        for (int p = 0; p < 4; ++p) {
            kr[p]  = *(const float4*)&k_lds[d][p][ksub * 4];
            qr[p]  = *(const float4*)&q_lds[d][p][ksub * 4];
            vr[p]  = v_lds[d][p][c4];
            scr[p] = *(const float4*)&s_lds[d][p][0];
        }
        BODY( 0,1); BODY( 1,1); BODY( 2,1); BODY( 3,1);
        BODY( 4,1); BODY( 5,1); BODY( 6,1); BODY( 7,1);
        BODY( 8,1); BODY( 9,1); BODY(10,1); BODY(11,1);
        BODY(12,1); BODY(13,1); BODY(14,1); BODY(15,1);
        BODY(16,1); BODY(17,1); BODY(18,1); BODY(19,1);
        BODY(20,1); BODY(21,1); BODY(22,1); BODY(23,1);
        BODY(24,1); BODY(25,1); BODY(26,1); BODY(27,1);
        BODY(28,0); BODY(29,0); BODY(30,0); BODY(31,0);
        if (c + 1 < NCH) {          // next chunk resident before buffer flip
            asm volatile("s_waitcnt vmcnt(0)" ::: "memory");
            __builtin_amdgcn_sched_barrier(0);
        }
        d ^= 1;
    }

    // final state outputs (un-scale)
#pragma unroll
    for (int j = 0; j < 4; ++j)
        S_out[((size_t)bh * Kv + (ksub * 4 + j)) * Vv + col] = Dn * S[j];
    b_out[(size_t)bh * Vv + col] = Dn * bv;   // dup lanes, same value
}

extern "C" void kernel_launch(void* const* d_in, const int* in_sizes, int n_in,
                              void* d_out, int out_size, void* d_ws, size_t ws_size,
                              hipStream_t stream) {
    const float* q   = (const float*)d_in[0];
    const float* k   = (const float*)d_in[1];
    const float* v   = (const float*)d_in[2];
    const float* g   = (const float*)d_in[3];
    const float* bet = (const float*)d_in[4];
    const float* lq  = (const float*)d_in[5];
    const float* lk  = (const float*)d_in[6];
    const float* S0  = (const float*)d_in[7];
    const float* b0  = (const float*)d_in[8];

    float* out   = (float*)d_out;
    float* o_out = out;
    float* S_out = out + (size_t)Bv * Tv * Hv * Vv;
    float* b_out = S_out + (size_t)Bv * Hv * Kv * Vv;

    dim3 grid(Bv * Hv * 16);   // (b,h) x 16 column-groups = 256 blocks (1/CU)
    dim3 block(64);
    gdr1dc_kernel<<<grid, block, 0, stream>>>(q, k, v, g, bet, lq, lk, S0, b0,
                                              o_out, S_out, b_out);
}

// Round 10
// 454.049 us; speedup vs baseline: 1.3254x; 1.0711x over previous
//
#include <hip/hip_runtime.h>
#include <stdint.h>

constexpr int Bv = 2, Tv = 4096, Hv = 8, Kv = 64, Vv = 64;
constexpr int CH = 32;            // steps per staged chunk
constexpr int NCH = Tv / CH;      // 128 chunks

template <int CTRL>
__device__ __forceinline__ float dpp_add(float x) {
    int t = __builtin_amdgcn_update_dpp(0, __float_as_int(x), CTRL, 0xF, 0xF, true);
    return x + __int_as_float(t);
}
// full sum over each contiguous 16-lane row via DPP row_ror (validated r4-r6)
__device__ __forceinline__ float row16_sum(float x) {
    x = dpp_add<0x128>(x);  // row_ror:8
    x = dpp_add<0x124>(x);  // row_ror:4
    x = dpp_add<0x4E>(x);   // quad_perm [2,3,0,1]
    x = dpp_add<0xB1>(x);   // quad_perm [1,0,3,2]
    return x;
}

// async global->LDS, no destination VGPRs
__device__ __forceinline__ void gl_lds16(const float* g, float* l) {
    __builtin_amdgcn_global_load_lds(
        reinterpret_cast<uint32_t __attribute__((address_space(1)))*>(
            reinterpret_cast<uintptr_t>(g)),
        reinterpret_cast<uint32_t __attribute__((address_space(3)))*>(
            reinterpret_cast<uintptr_t>(l)),
        16, 0, 0);
}
__device__ __forceinline__ void gl_lds4(const float* g, float* l) {
    __builtin_amdgcn_global_load_lds(
        reinterpret_cast<uint32_t __attribute__((address_space(1)))*>(
            reinterpret_cast<uintptr_t>(g)),
        reinterpret_cast<uint32_t __attribute__((address_space(3)))*>(
            reinterpret_cast<uintptr_t>(l)),
        4, 0, 0);
}

// stage chunk -> buffer dd: 20 async VMEM ops total.
// MUST be followed by sched_barrier(0): these loads have no register
// consumers; without a fence the scheduler may sink them below the
// o-flush store, breaking the counted vmcnt(1) at chunk end.
#define STAGE(dd) do {                                                    \
    _Pragma("unroll")                                                     \
    for (int j = 0; j < 8; ++j) {                                         \
        gl_lds16(kp + j * 4 * Hv * Kv, &k_lds[dd][4 * j][0]);             \
        gl_lds16(qp + j * 4 * Hv * Kv, &q_lds[dd][4 * j][0]);             \
    }                                                                     \
    _Pragma("unroll")                                                     \
    for (int j = 0; j < 2; ++j) {                                         \
        gl_lds4(vp + j * 16 * Hv * Vv, &v_lds[dd][16 * j][0]);            \
        gl_lds4(sp + j * 16 * Hv,      &s_lds[dd][16 * j][0]);            \
    }                                                                     \
    kp += CH * Hv * Kv; qp += CH * Hv * Kv;                               \
    vp += CH * Hv * Vv; sp += CH * Hv;                                    \
} while (0)

// one recurrence step t (compile-time); ring slot s = t&3.
// blkr = {beta, lam_k}; gmr = {beta/gam, 0.125*gam, lamq*gam, gam}
#define BODY(t_, PF_) do {                                                \
    constexpr int t = (t_);                                               \
    constexpr int s = t & 3;                                              \
    const float bvl  = blkr[s].y * bv;        /* lam_k * b_hat */         \
    const float bevD = gmr[s].x * vr[s];      /* beta*v/gam (off path) */ \
    float a0 = kr[s].x * S[0], a1 = kr[s].y * S[1];                       \
    a0 = fmaf(kr[s].z, S[2], a0); a1 = fmaf(kr[s].w, S[3], a1);           \
    const float dot = row16_sum(a0 + a1);                                 \
    const float us  = fmaf(-blkr[s].x, dot + bvl, bevD);                  \
    S[0] = fmaf(kr[s].x, us, S[0]); S[1] = fmaf(kr[s].y, us, S[1]);       \
    S[2] = fmaf(kr[s].z, us, S[2]); S[3] = fmaf(kr[s].w, us, S[3]);       \
    bv = fmaf(blkr[s].y, us, bv);                                         \
    float o0 = qr[s].x * S[0], o1 = qr[s].y * S[1];                       \
    o0 = fmaf(qr[s].z, S[2], o0); o1 = fmaf(qr[s].w, S[3], o1);           \
    const float od = row16_sum(o0 + o1);                                  \
    addr_o[t * 4] = fmaf(gmr[s].y, od, gmr[s].z * bv);                    \
    if (PF_) {   /* refill slot s with step t+4 from LDS */               \
        kr[s]   = *(const float4*)(kb + (t + 4) * Kv + (ksub << 2));      \
        qr[s]   = *(const float4*)(qb + (t + 4) * Kv + (ksub << 2));      \
        vr[s]   = vb[(t + 4) * 4 + c4];                                   \
        blkr[s] = *(const float2*)(sbb + (t + 4) * 4 + 2);                \
        gmr[s]  = *(const float4*)(gma + (t + 4) * 4);                    \
    }                                                                     \
} while (0)

__global__ __launch_bounds__(64, 1)
void gdr1dc_kernel(const float* __restrict__ qg, const float* __restrict__ kg,
                   const float* __restrict__ vg, const float* __restrict__ gg,
                   const float* __restrict__ bg, const float* __restrict__ lqg,
                   const float* __restrict__ lkg, const float* __restrict__ S0,
                   const float* __restrict__ b0,
                   float* __restrict__ o_out, float* __restrict__ S_out,
                   float* __restrict__ b_out)
{
    const int bid  = blockIdx.x;
    const int slot = bid >> 3;                    // XCD swizzle: bid%8 = XCD
    const int bh   = (bid & 7) + 8 * (slot >> 4); // b*H + h
    const int cg   = slot & 15;                   // column group (4 cols)
    const int lane = threadIdx.x;                 // 0..63
    const int ksub = lane & 15;                   // which 4-slice of K
    const int c4   = lane >> 4;                   // 0..3
    const int col  = cg * 4 + c4;                 // output column v

    __shared__ float k_lds[2][CH][Kv];    // 16 KB
    __shared__ float q_lds[2][CH][Kv];    // 16 KB
    __shared__ float v_lds[2][CH][4];     // 1 KB
    __shared__ float s_lds[2][CH][4];     // 1 KB  {g, lam_q, beta, lam_k}
    __shared__ float gma_lds[CH][4];      // 512 B
    __shared__ float o_dump[288];         // [0,127] valid o; [128+] dump

    float S[4];
#pragma unroll
    for (int j = 0; j < 4; ++j)
        S[j] = S0[((size_t)bh * Kv + (ksub * 4 + j)) * Vv + col];
    float bv = b0[(size_t)bh * Vv + col];

    const int b = bh / Hv, h = bh % Hv;
    const size_t t0 = (size_t)b * Tv * Hv + h;
    const int HV = Hv * Vv;

    const float* kp = kg + (t0 + (size_t)(lane >> 4) * Hv) * Kv + (lane & 15) * 4;
    const float* qp = qg + (t0 + (size_t)(lane >> 4) * Hv) * Kv + (lane & 15) * 4;
    const float* vp = vg + (t0 + (size_t)(lane >> 2) * Hv) * Vv + cg * 4 + (lane & 3);
    const float* sb = ((lane & 3) == 0) ? gg : ((lane & 3) == 1) ? lqg
                    : ((lane & 3) == 2) ? bg : lkg;
    const float* sp = sb + t0 + (size_t)(lane >> 2) * Hv;

    float* opf = o_out + (t0 + (size_t)(lane >> 1) * Hv) * Vv + cg * 4 + (lane & 1) * 2;
    float* addr_o = &o_dump[(ksub == 0) ? c4 : (128 + (lane & 31))];
    const float* gma = &gma_lds[0][0];

    float4 kr[4], qr[4], gmr[4];
    float2 blkr[4];
    float  vr[4];

    int d = 0;
    STAGE(0);
    __builtin_amdgcn_sched_barrier(0);
    asm volatile("s_waitcnt vmcnt(0)" ::: "memory");
    __builtin_amdgcn_sched_barrier(0);

    for (int c = 0; c < NCH; ++c) {
        if (c + 1 < NCH) {
            STAGE(d ^ 1);                       // 20 loads for chunk c+1
            __builtin_amdgcn_sched_barrier(0);  // pin them OLDEST
        }

        const float* kb  = &k_lds[d][0][0];
        const float* qb  = &q_lds[d][0][0];
        const float* vb  = &v_lds[d][0][0];
        const float* sbb = &s_lds[d][0][0];

        // ---- per-chunk gamma precompute (lanes 0..31 <-> steps 0..31) ----
        // Scan via guarded __shfl_up ladder (validated path), NOT DPP
        // row_shr/row_bcast (round-8/9 suspect: deterministic corruption).
        float Gam;
        {
            const float4 sc4 = *(const float4*)(sbb + (lane & 31) * 4);
            float G = sc4.x;                      // g_t
#pragma unroll
            for (int dd2 = 1; dd2 < 32; dd2 <<= 1) {
                float y = __shfl_up(G, dd2, 32);
                if ((lane & 31) >= dd2) G += y;   // inclusive prefix over 32
            }
            // chunk total via width-32 butterfly: every lane gets sum g_0..31
            float Gt = sc4.x;
            Gt += __shfl_xor(Gt, 1, 32);
            Gt += __shfl_xor(Gt, 2, 32);
            Gt += __shfl_xor(Gt, 4, 32);
            Gt += __shfl_xor(Gt, 8, 32);
            Gt += __shfl_xor(Gt, 16, 32);
            Gam = __expf(Gt);
            const float gam  = __expf(G);
            const float invg = __builtin_amdgcn_rcpf(gam);
            if (lane < 32) {
                float4 trio;
                trio.x = sc4.z * invg;            // beta/gamma
                trio.y = 0.125f * gam;            // scale*gamma
                trio.z = sc4.y * gam;             // lam_q*gamma
                trio.w = gam;
                *(float4*)(gma_lds[lane]) = trio;
            }
        }

        // ring prologue: steps 0..3
#pragma unroll
        for (int p = 0; p < 4; ++p) {
            kr[p]   = *(const float4*)(kb + p * Kv + (ksub << 2));
            qr[p]   = *(const float4*)(qb + p * Kv + (ksub << 2));
            vr[p]   = vb[p * 4 + c4];
            blkr[p] = *(const float2*)(sbb + p * 4 + 2);
            gmr[p]  = *(const float4*)(gma + p * 4);
        }

        BODY( 0,1); BODY( 1,1); BODY( 2,1); BODY( 3,1);
        BODY( 4,1); BODY( 5,1); BODY( 6,1); BODY( 7,1);
        BODY( 8,1); BODY( 9,1); BODY(10,1); BODY(11,1);
        BODY(12,1); BODY(13,1); BODY(14,1); BODY(15,1);
        BODY(16,1); BODY(17,1); BODY(18,1); BODY(19,1);
        BODY(20,1); BODY(21,1); BODY(22,1); BODY(23,1);
        BODY(24,1); BODY(25,1); BODY(26,1); BODY(27,1);
        BODY(28,0); BODY(29,0); BODY(30,0); BODY(31,0);

        // ---- flush o (128 floats); pin the store YOUNGEST ----
        __builtin_amdgcn_sched_barrier(0);
        {
            const float2 ov = *(const float2*)&o_dump[lane * 2];
            *(float2*)opf = ov;
            opf += (size_t)CH * HV;
        }
        __builtin_amdgcn_sched_barrier(0);

        // chunk-end rescale to true frame
#pragma unroll
        for (int j = 0; j < 4; ++j) S[j] *= Gam;
        bv *= Gam;

        // order pinned: 20 staged loads oldest, flush store youngest ->
        // vmcnt(1) drains exactly the staged loads, store flies on.
        asm volatile("s_waitcnt vmcnt(1)" ::: "memory");
        __builtin_amdgcn_sched_barrier(0);
        d ^= 1;
    }

#pragma unroll
    for (int j = 0; j < 4; ++j)
        S_out[((size_t)bh * Kv + (ksub * 4 + j)) * Vv + col] = S[j];
    b_out[(size_t)bh * Vv + col] = bv;
}

extern "C" void kernel_launch(void* const* d_in, const int* in_sizes, int n_in,
                              void* d_out, int out_size, void* d_ws, size_t ws_size,
                              hipStream_t stream) {
    const float* q   = (const float*)d_in[0];
    const float* k   = (const float*)d_in[1];
    const float* v   = (const float*)d_in[2];
    const float* g   = (const float*)d_in[3];
    const float* bet = (const float*)d_in[4];
    const float* lq  = (const float*)d_in[5];
    const float* lk  = (const float*)d_in[6];
    const float* S0  = (const float*)d_in[7];
    const float* b0  = (const float*)d_in[8];

    float* out   = (float*)d_out;
    float* o_out = out;
    float* S_out = out + (size_t)Bv * Tv * Hv * Vv;
    float* b_out = S_out + (size_t)Bv * Hv * Kv * Vv;

    dim3 grid(Bv * Hv * 16);   // (b,h) x 16 column-groups = 256 blocks (1/CU)
    dim3 block(64);
    gdr1dc_kernel<<<grid, block, 0, stream>>>(q, k, v, g, bet, lq, lk, S0, b0,
                                              o_out, S_out, b_out);
}